// Round 1
// baseline (365.597 us; speedup 1.0000x reference)
//
#include <hip/hip_runtime.h>

#define IN_DIM 128
#define H1 32
#define H2 16

// ---------------- degree count (col side, self-loop added in k_dinv) ----------
__global__ void k_count(const int* __restrict__ col, float* __restrict__ deg, int E) {
    int e = blockIdx.x * blockDim.x + threadIdx.x;
    if (e < E) atomicAdd(&deg[col[e]], 1.0f);
}

__global__ void k_dinv(float* __restrict__ deg, int N) {
    int i = blockIdx.x * blockDim.x + threadIdx.x;
    if (i < N) deg[i] = rsqrtf(deg[i] + 1.0f);   // +1 = self loop; deg>0 always
}

// ---------------- dense projection: hout[N][OD] = xin[N][KD] @ W[KD][OD] ------
template <int KD, int OD>
__global__ void k_mm(const float* __restrict__ xin, const float* __restrict__ W,
                     float* __restrict__ hout, int N) {
    __shared__ float Ws[KD * OD];
    for (int t = threadIdx.x; t < KD * OD; t += blockDim.x) Ws[t] = W[t];
    __syncthreads();
    int idx = blockIdx.x * blockDim.x + threadIdx.x;
    int i = idx / OD, d = idx % OD;
    if (i >= N) return;
    const float* xr = xin + (long)i * KD;
    float acc = 0.f;
#pragma unroll
    for (int k = 0; k < KD; ++k) acc = fmaf(xr[k], Ws[k * OD + d], acc);
    hout[idx] = acc;
}

// ---------------- edge scatter: agg[c][d] += hin[r][d] * dinv[r]*dinv[c] ------
template <int D>
__global__ void k_scatter(const int* __restrict__ row, const int* __restrict__ col,
                          const float* __restrict__ dinv, const float* __restrict__ hin,
                          float* __restrict__ agg, int E) {
    int idx = blockIdx.x * blockDim.x + threadIdx.x;
    int e = idx / D, d = idx % D;   // consecutive lanes share e -> broadcast idx loads, coalesced h
    if (e >= E) return;
    int r = row[e], c = col[e];
    float nrm = dinv[r] * dinv[c];
    atomicAdd(&agg[(long)c * D + d], hin[(long)r * D + d] * nrm);
}

// ---------------- self-loop + bias (+relu): agg = act(agg + h*dinv^2 + b) -----
template <int D, bool RELU>
__global__ void k_finish(const float* __restrict__ hproj, const float* __restrict__ dinv,
                         const float* __restrict__ bias, float* __restrict__ agg, int N) {
    int idx = blockIdx.x * blockDim.x + threadIdx.x;
    if (idx >= N * D) return;
    int i = idx / D, d = idx % D;
    float di = dinv[i];
    float v = agg[idx] + hproj[idx] * di * di + bias[d];
    agg[idx] = RELU ? fmaxf(v, 0.f) : v;
}

// ---------------- decode: out[i][j] = dot(z[i], z[j]), 64x64 tile / 4x4 thread
#define DTILE 64
#define DPAD 20   // padded row stride in floats; 80B keeps float4 alignment, breaks bank aliasing

__global__ void k_decode(const float* __restrict__ z, float* __restrict__ out, int N) {
    __shared__ float zi[DTILE * DPAD];
    __shared__ float zj[DTILE * DPAD];
    int bi = blockIdx.y * DTILE, bj = blockIdx.x * DTILE;
    int t = threadIdx.x;
    {
        int rr = t >> 2, cc = (t & 3) * 4;   // 256 threads: one float4 each per tile
        int gi = bi + rr, gj = bj + rr;
        float4 vi = make_float4(0.f, 0.f, 0.f, 0.f), vj = vi;
        if (gi < N) vi = *reinterpret_cast<const float4*>(&z[(long)gi * H2 + cc]);
        if (gj < N) vj = *reinterpret_cast<const float4*>(&z[(long)gj * H2 + cc]);
        *reinterpret_cast<float4*>(&zi[rr * DPAD + cc]) = vi;
        *reinterpret_cast<float4*>(&zj[rr * DPAD + cc]) = vj;
    }
    __syncthreads();
    int tx = t & 15, ty = t >> 4;
    float acc[4][4] = {};
#pragma unroll
    for (int kc = 0; kc < 4; ++kc) {
        float4 a[4], b[4];
#pragma unroll
        for (int u = 0; u < 4; ++u)
            a[u] = *reinterpret_cast<const float4*>(&zi[(ty * 4 + u) * DPAD + kc * 4]);
#pragma unroll
        for (int v = 0; v < 4; ++v)
            b[v] = *reinterpret_cast<const float4*>(&zj[(tx * 4 + v) * DPAD + kc * 4]);
#pragma unroll
        for (int u = 0; u < 4; ++u)
#pragma unroll
            for (int v = 0; v < 4; ++v)
                acc[u][v] += a[u].x * b[v].x + a[u].y * b[v].y +
                             a[u].z * b[v].z + a[u].w * b[v].w;
    }
#pragma unroll
    for (int u = 0; u < 4; ++u) {
        int gi = bi + ty * 4 + u;
        if (gi >= N) continue;
        int gj = bj + tx * 4;
        long base = (long)gi * N + gj;
        if (gj + 3 < N) {
            *reinterpret_cast<float4*>(&out[base]) =
                make_float4(acc[u][0], acc[u][1], acc[u][2], acc[u][3]);
        } else {
            for (int v2 = 0; v2 < 4; ++v2)
                if (gj + v2 < N) out[base + v2] = acc[u][v2];
        }
    }
}

extern "C" void kernel_launch(void* const* d_in, const int* in_sizes, int n_in,
                              void* d_out, int out_size, void* d_ws, size_t ws_size,
                              hipStream_t stream) {
    const float* x  = (const float*)d_in[0];
    const int*   ei = (const int*)d_in[1];
    const float* W1 = (const float*)d_in[2];
    const float* b1 = (const float*)d_in[3];
    const float* W2 = (const float*)d_in[4];
    const float* b2 = (const float*)d_in[5];
    float* out = (float*)d_out;

    const int N = in_sizes[0] / IN_DIM;   // 10000
    const int E = in_sizes[1] / 2;        // 640000
    const int* row = ei;
    const int* col = ei + E;

    float* w    = (float*)d_ws;
    float* dinv = w;                       // N
    float* h    = dinv + N;                // N*H1  (x@W1)
    float* h1   = h + (long)N * H1;        // N*H1  (agg1 -> relu'd hidden)
    float* h2   = h1 + (long)N * H1;       // N*H2  (h1@W2)
    float* zz   = h2 + (long)N * H2;       // N*H2  (agg2 -> z)

    hipMemsetAsync(dinv, 0, (size_t)N * sizeof(float), stream);
    hipMemsetAsync(h1,   0, (size_t)N * H1 * sizeof(float), stream);
    hipMemsetAsync(zz,   0, (size_t)N * H2 * sizeof(float), stream);

    k_count<<<(E + 255) / 256, 256, 0, stream>>>(col, dinv, E);
    k_dinv<<<(N + 255) / 256, 256, 0, stream>>>(dinv, N);

    k_mm<IN_DIM, H1><<<((long)N * H1 + 255) / 256, 256, 0, stream>>>(x, W1, h, N);
    k_scatter<H1><<<((long)E * H1 + 255) / 256, 256, 0, stream>>>(row, col, dinv, h, h1, E);
    k_finish<H1, true><<<((long)N * H1 + 255) / 256, 256, 0, stream>>>(h, dinv, b1, h1, N);

    k_mm<H1, H2><<<((long)N * H2 + 255) / 256, 256, 0, stream>>>(h1, W2, h2, N);
    k_scatter<H2><<<((long)E * H2 + 255) / 256, 256, 0, stream>>>(row, col, dinv, h2, zz, E);
    k_finish<H2, false><<<((long)N * H2 + 255) / 256, 256, 0, stream>>>(h2, dinv, b2, zz, N);

    dim3 dgrid((N + DTILE - 1) / DTILE, (N + DTILE - 1) / DTILE);
    k_decode<<<dgrid, 256, 0, stream>>>(zz, out, N);
}